// Round 5
// baseline (123.419 us; speedup 1.0000x reference)
//
#include <hip/hip_runtime.h>

// MLP: 64 × (Linear(5,5)+ReLU) then Linear(5,1), BATCH = 1048576 rows.
// fp32 VALU issue-bound. R13: weights via CONSTANT-ADDRSPACE loads -> SGPRs.
//
// R12 post-mortem: hand-rolled multi-output s_load inline asm aborted the
// build/run (matches this problem's history of asm-island allocator
// crashes). Zero information gained. Same experiment, safe mechanism:
// cast Ws/bs to __attribute__((address_space(4))) — AMDGPU constant AS,
// same 64-bit VA as global, so an integer cast of the flat pointer is
// valid. Uniform loads from AS(4) are selected as s_load by the backend
// itself: legal merging, its own lgkmcnt, its own scheduling. No asm.
//
// Why this tests the remaining hypothesis: three LDS/VGPR-path variants
// all sit at 51-53 µs = ~76% of the m07 103 TF sustained v_fma issue
// ceiling, gap scaling per-FMA (R11 killed DS-count & per-layer-overhead
// theories). Either (c1) the weight path costs ~30% extra VALU slots
// (per-use ds_read re-issue + movs, invisible in our counters), or (c2)
// clock-limited roofline. Here the weights live in SGPRs — v_fma_f32's
// one legal scalar operand — so there is NO weight traffic on the
// VALU/DS pipes at all. Bias needs a 2nd scalar read, so the compiler
// inserts 5 bias v_movs/layer (amortized over 4 rows). Ideal per layer
// per thread: 125 VALU (100 v_fma + 20 v_max + 5 v_mov) + ~9-25 SMEM
// (scalar pipe, hidden by 4 waves/SIMD) + 0 DS.
//
// Pre-committed read: LDS_Block_Size->0 & SGPR_Count->~90 = mechanism
// took. Then: 40-44 µs => c1 confirmed; ~51 µs => clock roofline, four
// disjoint implementations agree -> declare done.

#define MLP_DEPTH 64
#define MLP_D 5
#define ROWS 4

// Constant-address-space pointer: uniform loads select as s_load (SMEM).
typedef const float __attribute__((address_space(4)))* cfp;

__global__ __launch_bounds__(256, 4) void MLP_89687507075104_kernel(
    const float* __restrict__ x,      // [n, 5]
    const float* __restrict__ Ws,     // [64, 5, 5]
    const float* __restrict__ bs,     // [64, 5]
    const float* __restrict__ W_out,  // [1, 5]
    const float* __restrict__ b_out,  // [1]
    float* __restrict__ out,          // [n]
    int n)
{
    const cfp cWs = (cfp)(unsigned long long)Ws;
    const cfp cbs = (cfp)(unsigned long long)bs;
    const cfp cWo = (cfp)(unsigned long long)W_out;
    const cfp cbo = (cfp)(unsigned long long)b_out;

    const int t = blockIdx.x * blockDim.x + threadIdx.x;
    const long row0 = (long)t * ROWS;
    if (row0 >= n) return;

    // rows row0..row0+3 = 20 contiguous floats (80 B, 16B-aligned).
    const float4* xp = reinterpret_cast<const float4*>(x + row0 * MLP_D);
    const float4 q0 = xp[0], q1 = xp[1], q2 = xp[2], q3 = xp[3], q4 = xp[4];
    float h[ROWS][MLP_D];
    h[0][0]=q0.x; h[0][1]=q0.y; h[0][2]=q0.z; h[0][3]=q0.w; h[0][4]=q1.x;
    h[1][0]=q1.y; h[1][1]=q1.z; h[1][2]=q1.w; h[1][3]=q2.x; h[1][4]=q2.y;
    h[2][0]=q2.z; h[2][1]=q2.w; h[2][2]=q3.x; h[2][3]=q3.y; h[2][4]=q3.z;
    h[3][0]=q3.w; h[3][1]=q4.x; h[3][2]=q4.y; h[3][3]=q4.z; h[3][4]=q4.w;

#pragma unroll 2
    for (int l = 0; l < MLP_DEPTH; ++l) {
        // Uniform scalar loads -> s_load into SGPRs (backend merges what
        // alignment allows). W stays in SGPR SSA values; each v_fma reads
        // one as its single legal scalar operand.
        float W[25], b[MLP_D];
        const cfp wl = cWs + l * 25;
        const cfp bl = cbs + l * MLP_D;
#pragma unroll
        for (int k = 0; k < 25; ++k) W[k] = wl[k];
#pragma unroll
        for (int j = 0; j < MLP_D; ++j) b[j] = bl[j];

        // Row-fused compute+ReLU, i-outer/j-inner: 5 independent FMA
        // chains per row cover VALU latency. Identical arithmetic order
        // to all prior rounds (absmax must stay 0).
#pragma unroll
        for (int r = 0; r < ROWS; ++r) {
            float acc[MLP_D];
#pragma unroll
            for (int j = 0; j < MLP_D; ++j)
                acc[j] = fmaf(h[r][0], W[j * MLP_D + 0], b[j]);
#pragma unroll
            for (int i = 1; i < MLP_D; ++i)
#pragma unroll
                for (int j = 0; j < MLP_D; ++j)
                    acc[j] = fmaf(h[r][i], W[j * MLP_D + i], acc[j]);
#pragma unroll
            for (int j = 0; j < MLP_D; ++j)
                h[r][j] = fmaxf(acc[j], 0.0f);
        }
    }

    // Output layer: Linear(5,1) — scalar weights via the same SMEM path.
    const float wo0 = cWo[0], wo1 = cWo[1], wo2 = cWo[2], wo3 = cWo[3];
    const float wo4 = cWo[4], bo = cbo[0];
    float o[ROWS];
#pragma unroll
    for (int r = 0; r < ROWS; ++r) {
        float acc = fmaf(h[r][0], wo0, bo);
        acc = fmaf(h[r][1], wo1, acc);
        acc = fmaf(h[r][2], wo2, acc);
        acc = fmaf(h[r][3], wo3, acc);
        acc = fmaf(h[r][4], wo4, acc);
        o[r] = acc;
    }
    float4 ov;
    ov.x = o[0]; ov.y = o[1]; ov.z = o[2]; ov.w = o[3];
    *reinterpret_cast<float4*>(out + row0) = ov;
}

extern "C" void kernel_launch(void* const* d_in, const int* in_sizes, int n_in,
                              void* d_out, int out_size, void* d_ws, size_t ws_size,
                              hipStream_t stream) {
    const float* x     = (const float*)d_in[0];
    const float* Ws    = (const float*)d_in[1];
    const float* bs    = (const float*)d_in[2];
    const float* W_out = (const float*)d_in[3];
    const float* b_out = (const float*)d_in[4];
    float* out = (float*)d_out;

    const int n = in_sizes[0] / MLP_D;  // batch rows (1048576)
    const int block = 256;
    const int threads_needed = (n + ROWS - 1) / ROWS;
    const int grid = (threads_needed + block - 1) / block;  // 1024
    MLP_89687507075104_kernel<<<grid, block, 0, stream>>>(
        x, Ws, bs, W_out, b_out, out, n);
}

// Round 6
// 116.491 us; speedup vs baseline: 1.0595x; 1.0595x over previous
//
#include <hip/hip_runtime.h>

// MLP: 64 × (Linear(5,5)+ReLU) then Linear(5,1), BATCH = 1048576 rows.
// fp32 VALU issue-bound. R14: packed fp32 — v_pk_fma_f32 via <2 x float>.
//
// R13 post-mortem: SGPR/SMEM weight path took (LDS=0, SGPR=96, VGPR=24,
// minimal 125-slot/layer scalar VALU stream) yet VALU-busy time was
// 60µs × 80% ≈ 48µs ≈ R8's 51µs × 100%. So R8's schedule was never fat:
// ~51 µs IS the scalar v_fma_f32 issue wall at the sustained clock
// (~1.25 GHz under this workload). Four disjoint implementations agree.
// The per-FMA-overhead theory (c1) is dead.
//
// Only way down: fewer issue slots per FLOP. CDNA has VOP3P
// v_pk_fma_f32 (2 FMAs / instruction on 64-bit register pairs, op_sel
// splat-folding for uniform operands). gfx950 rate is the one untested
// 2× lever. Mechanism: pair rows (0,1),(2,3) into float2;
// __builtin_elementwise_fma on <2 x float> selects v_pk_fma_f32; the
// scalar W/b operands splat-fold via op_sel (no duplication movs if the
// backend folds — worst case it inserts movs and we learn that).
// Per layer per thread: 50 pk_fma + 20 v_max = 70 slots vs 120.
//
// Weights stay on the proven-best LDS broadcast path (R8) — R13 showed
// the SMEM path stalls (80% busy), which would dominate at halved
// compute. Per-chain fmaf order unchanged -> absmax 0.0.
//
// Pre-committed read: ~30-36 µs dispatch => pk full-rate, new regime;
// ~51 µs => pk half-rate (wash); >53 µs => scalarized/mov-burdened.
// Either non-win confirms the scalar-issue roofline from both sides ->
// revert to R8, declare done.

#define MLP_DEPTH 64
#define MLP_D 5
#define ROWS 4

typedef float f2 __attribute__((ext_vector_type(2)));

static __device__ __forceinline__ f2 splat2(float v) {
    f2 r; r.x = v; r.y = v; return r;
}

// LDS layout: layer l at sw[l*32]: k<25 -> W[j*5+i] (k=j*5+i), 25..29 -> b[j],
// 30..31 pad. Then at sw[2048]: W_out[0..4], b_out, pad, pad. Total 2056.
#define LDS_N 2056

__global__ __launch_bounds__(256, 4) void MLP_89687507075104_kernel(
    const float* __restrict__ x,      // [n, 5]
    const float* __restrict__ Ws,     // [64, 5, 5]
    const float* __restrict__ bs,     // [64, 5]
    const float* __restrict__ W_out,  // [1, 5]
    const float* __restrict__ b_out,  // [1]
    float* __restrict__ out,          // [n]
    int n)
{
    __shared__ float sw[LDS_N];
    for (int idx = threadIdx.x; idx < LDS_N; idx += 256) {
        float v;
        if (idx < MLP_DEPTH * 32) {
            const int l = idx >> 5, k = idx & 31;
            v = (k < 25) ? Ws[l * 25 + k]
              : (k < 30) ? bs[l * MLP_D + (k - 25)]
              : 0.0f;
        } else {
            const int k = idx - MLP_DEPTH * 32;
            v = (k < MLP_D) ? W_out[k] : (k == MLP_D) ? b_out[0] : 0.0f;
        }
        sw[idx] = v;
    }
    __syncthreads();

    const int t = blockIdx.x * blockDim.x + threadIdx.x;
    const long row0 = (long)t * ROWS;
    if (row0 >= n) return;

    // rows row0..row0+3 = 20 contiguous floats (80 B, 16B-aligned).
    const float4* xp = reinterpret_cast<const float4*>(x + row0 * MLP_D);
    const float4 q0 = xp[0], q1 = xp[1], q2 = xp[2], q3 = xp[3], q4 = xp[4];
    // h2[p][i] = (h[2p][i], h[2p+1][i]) — row-paired into register pairs.
    f2 h2[2][MLP_D];
    h2[0][0].x=q0.x; h2[0][1].x=q0.y; h2[0][2].x=q0.z; h2[0][3].x=q0.w; h2[0][4].x=q1.x;
    h2[0][0].y=q1.y; h2[0][1].y=q1.z; h2[0][2].y=q1.w; h2[0][3].y=q2.x; h2[0][4].y=q2.y;
    h2[1][0].x=q2.z; h2[1][1].x=q2.w; h2[1][2].x=q3.x; h2[1][3].x=q3.y; h2[1][4].x=q3.z;
    h2[1][0].y=q3.w; h2[1][1].y=q4.x; h2[1][2].y=q4.y; h2[1][3].y=q4.z; h2[1][4].y=q4.w;

#pragma unroll 2
    for (int l = 0; l < MLP_DEPTH; ++l) {
        // 8× ds_read_b128, broadcast (all lanes same address), offsets are
        // immediates off one per-layer base -> no per-read address VALU.
        const float4* wq = reinterpret_cast<const float4*>(&sw[l * 32]);
        float W[32];
#pragma unroll
        for (int m = 0; m < 8; ++m) {
            const float4 c = wq[m];
            W[4*m+0] = c.x; W[4*m+1] = c.y; W[4*m+2] = c.z; W[4*m+3] = c.w;
        }

        // Packed row-fused compute+ReLU. 10 independent pk_fma chains
        // (2 row-pairs × 5 outputs) cover VALU latency. Each half-lane
        // runs the exact scalar fmaf chain of prior rounds.
#pragma unroll
        for (int p = 0; p < 2; ++p) {
            f2 acc[MLP_D];
#pragma unroll
            for (int j = 0; j < MLP_D; ++j)
                acc[j] = __builtin_elementwise_fma(
                    h2[p][0], splat2(W[j * MLP_D + 0]), splat2(W[25 + j]));
#pragma unroll
            for (int i = 1; i < MLP_D; ++i)
#pragma unroll
                for (int j = 0; j < MLP_D; ++j)
                    acc[j] = __builtin_elementwise_fma(
                        h2[p][i], splat2(W[j * MLP_D + i]), acc[j]);
#pragma unroll
            for (int j = 0; j < MLP_D; ++j)
                h2[p][j] = __builtin_elementwise_max(acc[j], splat2(0.0f));
        }
    }

    // Output layer: Linear(5,1) — packed as well (2 pk_fma chains).
    const float4* oq = reinterpret_cast<const float4*>(&sw[MLP_DEPTH * 32]);
    const float4 c0 = oq[0], c1 = oq[1];
    f2 o2[2];
#pragma unroll
    for (int p = 0; p < 2; ++p) {
        f2 acc = __builtin_elementwise_fma(h2[p][0], splat2(c0.x), splat2(c1.y));
        acc = __builtin_elementwise_fma(h2[p][1], splat2(c0.y), acc);
        acc = __builtin_elementwise_fma(h2[p][2], splat2(c0.z), acc);
        acc = __builtin_elementwise_fma(h2[p][3], splat2(c0.w), acc);
        acc = __builtin_elementwise_fma(h2[p][4], splat2(c1.x), acc);
        o2[p] = acc;
    }
    float4 ov;
    ov.x = o2[0].x; ov.y = o2[0].y; ov.z = o2[1].x; ov.w = o2[1].y;
    *reinterpret_cast<float4*>(out + row0) = ov;
}

extern "C" void kernel_launch(void* const* d_in, const int* in_sizes, int n_in,
                              void* d_out, int out_size, void* d_ws, size_t ws_size,
                              hipStream_t stream) {
    const float* x     = (const float*)d_in[0];
    const float* Ws    = (const float*)d_in[1];
    const float* bs    = (const float*)d_in[2];
    const float* W_out = (const float*)d_in[3];
    const float* b_out = (const float*)d_in[4];
    float* out = (float*)d_out;

    const int n = in_sizes[0] / MLP_D;  // batch rows (1048576)
    const int block = 256;
    const int threads_needed = (n + ROWS - 1) / ROWS;
    const int grid = (threads_needed + block - 1) / block;  // 1024
    MLP_89687507075104_kernel<<<grid, block, 0, stream>>>(
        x, Ws, bs, W_out, b_out, out, n);
}

// Round 7
// 112.627 us; speedup vs baseline: 1.0958x; 1.0343x over previous
//
#include <hip/hip_runtime.h>

// MLP: 64 × (Linear(5,5)+ReLU) then Linear(5,1), BATCH = 1048576 rows.
// R15: ROWS=8 + packed v_pk_fma_f32 — attack BOTH pipes at once.
//
// R14 post-mortem: packing halved VALU slots (VALUBusy 100->61%, the
// exact 70/120 ratio) but time stayed 52 µs -> the DS pipe is the wall.
// Broadcast ds_read_b128 still writes 16 B to each of 64 lanes (1024 B
// of register-file writes), ~10-12 cyc each; 16 waves/CU × 8 reads =
// 128 b128/CU/layer ≈ 1280+ cyc vs packed-VALU 560 cyc/SIMD. 64 layers
// × 1280 cyc ≈ 51 µs @1.6 GHz — the wall every LDS variant hit.
// Retro-consistent: R11 (ROWS=8 scalar) halved DS to 640 but VALU 960
// bound at the same 53 µs; R14 halved VALU to 560 but DS 1280 bound.
// Each lever alone was masked by the other pipe. Apply both:
//   DS:   8 waves/CU × 8 b128 = 640 cyc/CU/layer
//   VALU: 2 waves/SIMD × 120 packed instr × 2 cyc = 480 cyc/SIMD/layer
// -> balanced ~640 cyc/layer -> ~26-34 µs dispatch predicted.
//
// Occupancy 2 waves/SIMD (131072 threads, 512 blocks); 20 independent
// pk-fma chains (4 row-pairs × 5 outputs) self-hide DS+VALU latency.
// ~110 VGPR under launch_bounds(256,2). Per-half-lane fmaf chain order
// identical to all prior rounds -> absmax 0.0.
//
// Pre-committed read: ~28-36 µs => DS-pipe model confirmed; ~52 µs =>
// model wrong, wall is issue/clock -> declare roofline on R8/R14 form.

#define MLP_DEPTH 64
#define MLP_D 5
#define ROWS 8

typedef float f2 __attribute__((ext_vector_type(2)));

static __device__ __forceinline__ f2 splat2(float v) {
    f2 r; r.x = v; r.y = v; return r;
}

// LDS layout: layer l at sw[l*32]: k<25 -> W[j*5+i] (k=j*5+i), 25..29 -> b[j],
// 30..31 pad. Then at sw[2048]: W_out[0..4], b_out, pad, pad. Total 2056.
#define LDS_N 2056

__global__ __launch_bounds__(256, 2) void MLP_89687507075104_kernel(
    const float* __restrict__ x,      // [n, 5]
    const float* __restrict__ Ws,     // [64, 5, 5]
    const float* __restrict__ bs,     // [64, 5]
    const float* __restrict__ W_out,  // [1, 5]
    const float* __restrict__ b_out,  // [1]
    float* __restrict__ out,          // [n]
    int n)
{
    __shared__ float sw[LDS_N];
    for (int idx = threadIdx.x; idx < LDS_N; idx += 256) {
        float v;
        if (idx < MLP_DEPTH * 32) {
            const int l = idx >> 5, k = idx & 31;
            v = (k < 25) ? Ws[l * 25 + k]
              : (k < 30) ? bs[l * MLP_D + (k - 25)]
              : 0.0f;
        } else {
            const int k = idx - MLP_DEPTH * 32;
            v = (k < MLP_D) ? W_out[k] : (k == MLP_D) ? b_out[0] : 0.0f;
        }
        sw[idx] = v;
    }
    __syncthreads();

    const int t = blockIdx.x * blockDim.x + threadIdx.x;
    const long row0 = (long)t * ROWS;
    if (row0 >= n) return;

    // rows row0..row0+7 = 40 contiguous floats (160 B, 16B-aligned).
    const float4* xp = reinterpret_cast<const float4*>(x + row0 * MLP_D);
    float tmp[ROWS * MLP_D];
#pragma unroll
    for (int m = 0; m < (ROWS * MLP_D) / 4; ++m) {
        const float4 c = xp[m];
        tmp[4*m+0] = c.x; tmp[4*m+1] = c.y; tmp[4*m+2] = c.z; tmp[4*m+3] = c.w;
    }
    // h2[p][i] = (h[2p][i], h[2p+1][i]) — row-paired into register pairs.
    f2 h2[ROWS / 2][MLP_D];
#pragma unroll
    for (int p = 0; p < ROWS / 2; ++p)
#pragma unroll
        for (int i = 0; i < MLP_D; ++i) {
            h2[p][i].x = tmp[(2 * p + 0) * MLP_D + i];
            h2[p][i].y = tmp[(2 * p + 1) * MLP_D + i];
        }

#pragma unroll 2
    for (int l = 0; l < MLP_DEPTH; ++l) {
        // 8× ds_read_b128, broadcast (all lanes same address), offsets are
        // immediates off one per-layer base -> no per-read address VALU.
        const float4* wq = reinterpret_cast<const float4*>(&sw[l * 32]);
        float W[32];
#pragma unroll
        for (int m = 0; m < 8; ++m) {
            const float4 c = wq[m];
            W[4*m+0] = c.x; W[4*m+1] = c.y; W[4*m+2] = c.z; W[4*m+3] = c.w;
        }

        // Packed row-fused compute+ReLU: 20 independent pk_fma chains
        // (4 row-pairs × 5 outputs). Each half-lane runs the exact
        // scalar fmaf chain of prior rounds.
#pragma unroll
        for (int p = 0; p < ROWS / 2; ++p) {
            f2 acc[MLP_D];
#pragma unroll
            for (int j = 0; j < MLP_D; ++j)
                acc[j] = __builtin_elementwise_fma(
                    h2[p][0], splat2(W[j * MLP_D + 0]), splat2(W[25 + j]));
#pragma unroll
            for (int i = 1; i < MLP_D; ++i)
#pragma unroll
                for (int j = 0; j < MLP_D; ++j)
                    acc[j] = __builtin_elementwise_fma(
                        h2[p][i], splat2(W[j * MLP_D + i]), acc[j]);
#pragma unroll
            for (int j = 0; j < MLP_D; ++j)
                h2[p][j] = __builtin_elementwise_max(acc[j], splat2(0.0f));
        }
    }

    // Output layer: Linear(5,1) — packed (4 pk_fma chains).
    const float4* oq = reinterpret_cast<const float4*>(&sw[MLP_DEPTH * 32]);
    const float4 c0 = oq[0], c1 = oq[1];
    f2 o2[ROWS / 2];
#pragma unroll
    for (int p = 0; p < ROWS / 2; ++p) {
        f2 acc = __builtin_elementwise_fma(h2[p][0], splat2(c0.x), splat2(c1.y));
        acc = __builtin_elementwise_fma(h2[p][1], splat2(c0.y), acc);
        acc = __builtin_elementwise_fma(h2[p][2], splat2(c0.z), acc);
        acc = __builtin_elementwise_fma(h2[p][3], splat2(c0.w), acc);
        acc = __builtin_elementwise_fma(h2[p][4], splat2(c1.x), acc);
        o2[p] = acc;
    }
    float4 ov0, ov1;
    ov0.x = o2[0].x; ov0.y = o2[0].y; ov0.z = o2[1].x; ov0.w = o2[1].y;
    ov1.x = o2[2].x; ov1.y = o2[2].y; ov1.z = o2[3].x; ov1.w = o2[3].y;
    float4* op = reinterpret_cast<float4*>(out + row0);
    op[0] = ov0;
    op[1] = ov1;
}

extern "C" void kernel_launch(void* const* d_in, const int* in_sizes, int n_in,
                              void* d_out, int out_size, void* d_ws, size_t ws_size,
                              hipStream_t stream) {
    const float* x     = (const float*)d_in[0];
    const float* Ws    = (const float*)d_in[1];
    const float* bs    = (const float*)d_in[2];
    const float* W_out = (const float*)d_in[3];
    const float* b_out = (const float*)d_in[4];
    float* out = (float*)d_out;

    const int n = in_sizes[0] / MLP_D;  // batch rows (1048576)
    const int block = 256;
    const int threads_needed = (n + ROWS - 1) / ROWS;
    const int grid = (threads_needed + block - 1) / block;  // 512
    MLP_89687507075104_kernel<<<grid, block, 0, stream>>>(
        x, Ws, bs, W_out, b_out, out, n);
}

// Round 8
// 107.602 us; speedup vs baseline: 1.1470x; 1.0467x over previous
//
#include <hip/hip_runtime.h>

// MLP: 64 × (Linear(5,5)+ReLU) then Linear(5,1), BATCH = 1048576 rows.
// R16: SGPR weights (constant-AS s_load, zero DS) + packed v_pk_fma_f32
//      + A/B double-buffered source-level s_load prefetch.
//
// Ledger through R15: every LDS variant sits at 51-53 µs while VALUBusy
// tracks the instruction count (R8 120/layer @100% -> R14 70/layer @61%
// -> R15 @56%): pk_fma IS full-rate, but the freed cycles are eaten by
// LDS-path stalls the compiler re-creates in every form (per-use ds_read
// re-issue; VGPR stuck at 32-52, never holding W). R13 (SGPR/SMEM path)
// is the exception: minimal 125-slot stream at 80% busy — its only sin
// was one unprefetched ~200-cyc s_load latency per layer (the idle 20%).
//
// This round combines the two proven-good halves, never yet tried
// together: weights live in SGPRs (v_pk_fma_f32 is VOP3P: one SGPR
// source, op_sel_hi splats it to both halves — weights never touch a
// VGPR), compute is packed (70/layer), and the per-layer SMEM latency is
// hidden by an A/B double buffer: loadB(l+1); computeA; loadA(l+2);
// computeB — each layer's s_loads issue ~140 packed-VALU cycles before
// use, plus 4 waves/SIMD cross-hiding. Zero DS instructions anywhere.
//
// Pre-committed read (tells: LDS=0, SGPR>=80, VGPR<=48):
//   ~28-36 µs => clean win, continue; ~42-48 @ ~95% busy => splat movs
//   materialized; ~60 @ ~65% => prefetch failed; ~52 => wall deeper than
//   pipe models -> declare roofline on R8.

#define MLP_DEPTH 64
#define MLP_D 5
#define ROWS 4

typedef float f2 __attribute__((ext_vector_type(2)));
// Constant-address-space pointer: uniform loads select as s_load (SMEM).
typedef const float __attribute__((address_space(4)))* cfp;

static __device__ __forceinline__ f2 splat2(float v) {
    f2 r; r.x = v; r.y = v; return r;
}

struct WB { float W[25]; float b[MLP_D]; };

static __device__ __forceinline__ void loadWB(WB& s, cfp cWs, cfp cbs, int l) {
    const cfp w = cWs + l * 25;
    const cfp bb = cbs + l * MLP_D;
#pragma unroll
    for (int k = 0; k < 25; ++k) s.W[k] = w[k];
#pragma unroll
    for (int j = 0; j < MLP_D; ++j) s.b[j] = bb[j];
}

// Packed row-fused layer: 2 row-pairs × 5 outputs = 10 independent
// pk_fma chains; each half-lane runs the exact fmaf chain of all prior
// rounds (absmax must stay 0.0). Weights/bias are wave-uniform SGPRs.
static __device__ __forceinline__ void computeWB(const WB& s, f2 h2[2][MLP_D]) {
#pragma unroll
    for (int p = 0; p < 2; ++p) {
        f2 acc[MLP_D];
#pragma unroll
        for (int j = 0; j < MLP_D; ++j)
            acc[j] = __builtin_elementwise_fma(
                h2[p][0], splat2(s.W[j * MLP_D + 0]), splat2(s.b[j]));
#pragma unroll
        for (int i = 1; i < MLP_D; ++i)
#pragma unroll
            for (int j = 0; j < MLP_D; ++j)
                acc[j] = __builtin_elementwise_fma(
                    h2[p][i], splat2(s.W[j * MLP_D + i]), acc[j]);
#pragma unroll
        for (int j = 0; j < MLP_D; ++j)
            h2[p][j] = __builtin_elementwise_max(acc[j], splat2(0.0f));
    }
}

__global__ __launch_bounds__(256, 4) void MLP_89687507075104_kernel(
    const float* __restrict__ x,      // [n, 5]
    const float* __restrict__ Ws,     // [64, 5, 5]
    const float* __restrict__ bs,     // [64, 5]
    const float* __restrict__ W_out,  // [1, 5]
    const float* __restrict__ b_out,  // [1]
    float* __restrict__ out,          // [n]
    int n)
{
    const cfp cWs = (cfp)(unsigned long long)Ws;
    const cfp cbs = (cfp)(unsigned long long)bs;
    const cfp cWo = (cfp)(unsigned long long)W_out;
    const cfp cbo = (cfp)(unsigned long long)b_out;

    const int t = blockIdx.x * blockDim.x + threadIdx.x;
    const long row0 = (long)t * ROWS;
    if (row0 >= n) return;

    // rows row0..row0+3 = 20 contiguous floats (80 B, 16B-aligned).
    const float4* xp = reinterpret_cast<const float4*>(x + row0 * MLP_D);
    const float4 q0 = xp[0], q1 = xp[1], q2 = xp[2], q3 = xp[3], q4 = xp[4];
    // h2[p][i] = (h[2p][i], h[2p+1][i]) — row-paired into register pairs.
    f2 h2[2][MLP_D];
    h2[0][0].x=q0.x; h2[0][1].x=q0.y; h2[0][2].x=q0.z; h2[0][3].x=q0.w; h2[0][4].x=q1.x;
    h2[0][0].y=q1.y; h2[0][1].y=q1.z; h2[0][2].y=q1.w; h2[0][3].y=q2.x; h2[0][4].y=q2.y;
    h2[1][0].x=q2.z; h2[1][1].x=q2.w; h2[1][2].x=q3.x; h2[1][3].x=q3.y; h2[1][4].x=q3.z;
    h2[1][0].y=q3.w; h2[1][1].y=q4.x; h2[1][2].y=q4.y; h2[1][3].y=q4.z; h2[1][4].y=q4.w;

    WB A, B;
    loadWB(A, cWs, cbs, 0);

#pragma unroll 1
    for (int l = 0; l < MLP_DEPTH; l += 2) {
        loadWB(B, cWs, cbs, l + 1);     // s_loads issue ~140 cyc before use
        computeWB(A, h2);
        // Clamp keeps the final (redundant) prefetch in-bounds.
        const int ln = (l + 2 < MLP_DEPTH) ? (l + 2) : (MLP_DEPTH - 1);
        loadWB(A, cWs, cbs, ln);
        computeWB(B, h2);
    }

    // Output layer: Linear(5,1) — packed (2 pk_fma chains), SGPR weights.
    const float wo0 = cWo[0], wo1 = cWo[1], wo2 = cWo[2], wo3 = cWo[3];
    const float wo4 = cWo[4], bo = cbo[0];
    f2 o2[2];
#pragma unroll
    for (int p = 0; p < 2; ++p) {
        f2 acc = __builtin_elementwise_fma(h2[p][0], splat2(wo0), splat2(bo));
        acc = __builtin_elementwise_fma(h2[p][1], splat2(wo1), acc);
        acc = __builtin_elementwise_fma(h2[p][2], splat2(wo2), acc);
        acc = __builtin_elementwise_fma(h2[p][3], splat2(wo3), acc);
        acc = __builtin_elementwise_fma(h2[p][4], splat2(wo4), acc);
        o2[p] = acc;
    }
    float4 ov;
    ov.x = o2[0].x; ov.y = o2[0].y; ov.z = o2[1].x; ov.w = o2[1].y;
    *reinterpret_cast<float4*>(out + row0) = ov;
}

extern "C" void kernel_launch(void* const* d_in, const int* in_sizes, int n_in,
                              void* d_out, int out_size, void* d_ws, size_t ws_size,
                              hipStream_t stream) {
    const float* x     = (const float*)d_in[0];
    const float* Ws    = (const float*)d_in[1];
    const float* bs    = (const float*)d_in[2];
    const float* W_out = (const float*)d_in[3];
    const float* b_out = (const float*)d_in[4];
    float* out = (float*)d_out;

    const int n = in_sizes[0] / MLP_D;  // batch rows (1048576)
    const int block = 256;
    const int threads_needed = (n + ROWS - 1) / ROWS;
    const int grid = (threads_needed + block - 1) / block;  // 1024
    MLP_89687507075104_kernel<<<grid, block, 0, stream>>>(
        x, Ws, bs, W_out, b_out, out, n);
}